// Round 1
// baseline (818.631 us; speedup 1.0000x reference)
//
#include <hip/hip_runtime.h>

#define IN_C 128
#define HID 96
#define OUT_C 64
#define W0C 288   // HID*3  (BN width)
#define W1C 192   // OUT_C*3

// ---------------- graph preprocessing ----------------

__global__ void k_zero(int* __restrict__ p, int n) {
    int i = blockIdx.x * blockDim.x + threadIdx.x;
    if (i < n) p[i] = 0;
}

__global__ void k_count(const int* __restrict__ col, int* __restrict__ counts, int e) {
    int i = blockIdx.x * blockDim.x + threadIdx.x;
    if (i < e) atomicAdd(&counts[col[i]], 1);
}

__global__ void k_dinv(const int* __restrict__ counts, float* __restrict__ dinv, int n) {
    int i = blockIdx.x * blockDim.x + threadIdx.x;
    if (i < n) dinv[i] = rsqrtf((float)(counts[i] + 1));
}

__global__ void k_block_sum(const int* __restrict__ counts, int* __restrict__ bsums, int n) {
    __shared__ int s[256];
    int i = blockIdx.x * 256 + threadIdx.x;
    s[threadIdx.x] = (i < n) ? counts[i] : 0;
    __syncthreads();
    for (int off = 128; off > 0; off >>= 1) {
        if (threadIdx.x < (unsigned)off) s[threadIdx.x] += s[threadIdx.x + off];
        __syncthreads();
    }
    if (threadIdx.x == 0) bsums[blockIdx.x] = s[0];
}

// single block; nb <= 256 (n=50000 -> nb=196)
__global__ void k_scan_bsums(int* __restrict__ bsums, int nb) {
    __shared__ int s[256];
    int v = ((int)threadIdx.x < nb) ? bsums[threadIdx.x] : 0;
    s[threadIdx.x] = v;
    __syncthreads();
    for (int off = 1; off < 256; off <<= 1) {
        int t = ((int)threadIdx.x >= off) ? s[threadIdx.x - off] : 0;
        __syncthreads();
        s[threadIdx.x] += t;
        __syncthreads();
    }
    if ((int)threadIdx.x < nb) bsums[threadIdx.x] = s[threadIdx.x] - v;  // exclusive
}

__global__ void k_row_ptr(const int* __restrict__ counts, const int* __restrict__ boffs,
                          int* __restrict__ row_ptr, int n) {
    __shared__ int s[256];
    int i = blockIdx.x * 256 + threadIdx.x;
    int v = (i < n) ? counts[i] : 0;
    s[threadIdx.x] = v;
    __syncthreads();
    for (int off = 1; off < 256; off <<= 1) {
        int t = ((int)threadIdx.x >= off) ? s[threadIdx.x - off] : 0;
        __syncthreads();
        s[threadIdx.x] += t;
        __syncthreads();
    }
    if (i < n) row_ptr[i] = boffs[blockIdx.x] + s[threadIdx.x] - v;  // exclusive
}

__global__ void k_fill(const int* __restrict__ row, const int* __restrict__ col,
                       const int* __restrict__ row_ptr, int* __restrict__ cursor,
                       const float* __restrict__ dinv,
                       int* __restrict__ csr_src, float* __restrict__ csr_w, int e) {
    int i = blockIdx.x * blockDim.x + threadIdx.x;
    if (i >= e) return;
    int c = col[i], r = row[i];
    int pos = row_ptr[c] + atomicAdd(&cursor[c], 1);
    csr_src[pos] = r;
    csr_w[pos] = dinv[r] * dinv[c];
}

// ---------------- SpMM (CSR by destination, gather, no atomics) ----------------
// out[node, :] = dinv[node]^2 * x[node, :] + sum_k w[k] * x[src[k], :]
// C4 float4-chunks per row; NPB nodes per block; blockDim = C4*NPB.
template <int C4, int NPB>
__global__ void k_spmm(const float* __restrict__ xin, int ldx,
                       float* __restrict__ xout, int ldo,
                       const int* __restrict__ row_ptr, const int* __restrict__ counts,
                       const int* __restrict__ csr_src, const float* __restrict__ csr_w,
                       const float* __restrict__ dinv, int n) {
    int c4 = threadIdx.x % C4;
    int nl = threadIdx.x / C4;
    int node = blockIdx.x * NPB + nl;
    if (node >= n) return;
    const float4* xi = (const float4*)xin;
    int ldx4 = ldx >> 2, ldo4 = ldo >> 2;
    float di = dinv[node];
    float lw = di * di;
    float4 v = xi[(size_t)node * ldx4 + c4];
    float4 acc;
    acc.x = lw * v.x; acc.y = lw * v.y; acc.z = lw * v.z; acc.w = lw * v.w;
    int start = row_ptr[node];
    int cnt = counts[node];
    for (int k = 0; k < cnt; k++) {
        int src = csr_src[start + k];
        float w = csr_w[start + k];
        float4 xv = xi[(size_t)src * ldx4 + c4];
        acc.x += w * xv.x; acc.y += w * xv.y; acc.z += w * xv.z; acc.w += w * xv.w;
    }
    ((float4*)xout)[(size_t)node * ldo4 + c4] = acc;
}

// ---------------- tiled fp32 GEMM: C = A(MxK) @ B(KxN) + bias ----------------
// BM=64 BN=64 BK=16, 256 threads, 4x4 per thread. K must be a multiple of 16.
#define BM 64
#define BN 64
#define BK 16

__global__ __launch_bounds__(256) void k_gemm(const float* __restrict__ A, int lda,
                                              const float* __restrict__ B, int ldb,
                                              const float* __restrict__ bias,
                                              float* __restrict__ C, int ldc,
                                              int M, int N, int K) {
    __shared__ float As[BK][BM];
    __shared__ float Bs[BK][BN];
    int tid = threadIdx.x;
    int tx = tid % 16, ty = tid / 16;
    int rowBase = blockIdx.x * BM;
    int colBase = blockIdx.y * BN;
    float acc[4][4] = {};
    for (int k0 = 0; k0 < K; k0 += BK) {
        for (int i = tid; i < BM * BK; i += 256) {
            int r = i / BK, c = i % BK;
            int gr = rowBase + r;
            As[c][r] = (gr < M) ? A[(size_t)gr * lda + (k0 + c)] : 0.f;
        }
        for (int i = tid; i < BK * BN; i += 256) {
            int r = i / BN, c = i % BN;
            int gc = colBase + c;
            Bs[r][c] = (gc < N) ? B[(size_t)(k0 + r) * ldb + gc] : 0.f;
        }
        __syncthreads();
#pragma unroll
        for (int kk = 0; kk < BK; kk++) {
            float a[4], b[4];
#pragma unroll
            for (int i = 0; i < 4; i++) a[i] = As[kk][ty * 4 + i];
#pragma unroll
            for (int j = 0; j < 4; j++) b[j] = Bs[kk][tx * 4 + j];
#pragma unroll
            for (int i = 0; i < 4; i++)
#pragma unroll
                for (int j = 0; j < 4; j++) acc[i][j] += a[i] * b[j];
        }
        __syncthreads();
    }
#pragma unroll
    for (int i = 0; i < 4; i++) {
        int r = rowBase + ty * 4 + i;
        if (r >= M) continue;
#pragma unroll
        for (int j = 0; j < 4; j++) {
            int c = colBase + tx * 4 + j;
            if (c < N) C[(size_t)r * ldc + c] = acc[i][j] + bias[c];
        }
    }
}

// ---------------- BatchNorm(eval) + ReLU ----------------

__global__ void k_bn_prep(const float* __restrict__ gamma, const float* __restrict__ beta,
                          const float* __restrict__ mean, const float* __restrict__ var,
                          float* __restrict__ scale, float* __restrict__ shift, int w) {
    int i = blockIdx.x * blockDim.x + threadIdx.x;
    if (i < w) {
        float s = gamma[i] * rsqrtf(var[i] + 1e-5f);
        scale[i] = s;
        shift[i] = beta[i] - mean[i] * s;
    }
}

__global__ void k_bn_relu(float4* __restrict__ h, const float* __restrict__ scale,
                          const float* __restrict__ shift, int total4, int w4) {
    int i = blockIdx.x * blockDim.x + threadIdx.x;
    if (i >= total4) return;
    int c4 = i % w4;
    float4 v = h[i];
    float4 sc = ((const float4*)scale)[c4];
    float4 sh = ((const float4*)shift)[c4];
    v.x = fmaxf(v.x * sc.x + sh.x, 0.f);
    v.y = fmaxf(v.y * sc.y + sh.y, 0.f);
    v.z = fmaxf(v.z * sc.z + sh.z, 0.f);
    v.w = fmaxf(v.w * sc.w + sh.w, 0.f);
    h[i] = v;
}

// ---------------- launch ----------------

extern "C" void kernel_launch(void* const* d_in, const int* in_sizes, int n_in,
                              void* d_out, int out_size, void* d_ws, size_t ws_size,
                              hipStream_t stream) {
    const int n = in_sizes[0] / IN_C;   // 50000
    const int e = in_sizes[1] / 2;      // 800000

    const float* x    = (const float*)d_in[0];
    const int*   ei   = (const int*)d_in[1];
    const float* W0   = (const float*)d_in[2];   // (3,128,96)
    const float* b0   = (const float*)d_in[3];   // (3,96)
    const float* W1   = (const float*)d_in[4];   // (3,288,64)
    const float* b1   = (const float*)d_in[5];   // (3,64)
    const float* bn_g = (const float*)d_in[6];
    const float* bn_b = (const float*)d_in[7];
    const float* bn_m = (const float*)d_in[8];
    const float* bn_v = (const float*)d_in[9];
    const float* Wf   = (const float*)d_in[10];  // (192,64)
    const float* bf   = (const float*)d_in[11];  // (64)
    float* out = (float*)d_out;

    const int* e_row = ei;
    const int* e_col = ei + e;

    // workspace layout (256B aligned)
    char* ws = (char*)d_ws;
    size_t off = 0;
    auto alloc = [&](size_t bytes) -> void* {
        void* p = ws + off;
        off += (bytes + 255) & ~(size_t)255;
        return p;
    };
    int*   counts  = (int*)alloc((size_t)2 * n * 4);   // counts + cursor contiguous
    int*   cursor  = counts + n;
    int*   row_ptr = (int*)alloc((size_t)n * 4);
    int*   bsums   = (int*)alloc(256 * 4);
    float* dinv    = (float*)alloc((size_t)n * 4);
    int*   csr_src = (int*)alloc((size_t)e * 4);
    float* csr_w   = (float*)alloc((size_t)e * 4);
    float* bnscale = (float*)alloc(W0C * 4);
    float* bnshift = (float*)alloc(W0C * 4);
    float* t1 = (float*)alloc((size_t)n * HID * 4);
    float* t2 = (float*)alloc((size_t)n * HID * 4);
    float* tp = (float*)alloc((size_t)n * HID * 4);
    float* h  = (float*)alloc((size_t)n * W0C * 4);
    float* g  = (float*)alloc((size_t)n * W1C * 4);
    // layer-1 temp buffers alias the (dead-by-then) t buffers
    float* u1 = t1;
    float* u2 = t2;
    float* up = tp;

    const int TB = 256;
    int nb = (n + 255) / 256;  // 196 (<=256 required by k_scan_bsums)

    // --- graph prep ---
    k_zero<<<dim3((2 * n + TB - 1) / TB), dim3(TB), 0, stream>>>(counts, 2 * n);
    k_count<<<dim3((e + TB - 1) / TB), dim3(TB), 0, stream>>>(e_col, counts, e);
    k_dinv<<<dim3((n + TB - 1) / TB), dim3(TB), 0, stream>>>(counts, dinv, n);
    k_block_sum<<<dim3(nb), dim3(256), 0, stream>>>(counts, bsums, n);
    k_scan_bsums<<<dim3(1), dim3(256), 0, stream>>>(bsums, nb);
    k_row_ptr<<<dim3(nb), dim3(256), 0, stream>>>(counts, bsums, row_ptr, n);
    k_fill<<<dim3((e + TB - 1) / TB), dim3(TB), 0, stream>>>(e_row, e_col, row_ptr, cursor,
                                                             dinv, csr_src, csr_w, e);

    // --- layer 0: x(n,128) @ W0[j](128,96) ---
    dim3 gemm_grid0((n + BM - 1) / BM, (HID + BN - 1) / BN);
    // j=0 -> h[:,0:96]
    k_gemm<<<gemm_grid0, dim3(256), 0, stream>>>(x, IN_C, W0 + 0 * IN_C * HID, HID,
                                                 b0 + 0 * HID, h, W0C, n, HID, IN_C);
    // j=1 -> t1 ; j=2 -> t2
    k_gemm<<<gemm_grid0, dim3(256), 0, stream>>>(x, IN_C, W0 + 1 * IN_C * HID, HID,
                                                 b0 + 1 * HID, t1, HID, n, HID, IN_C);
    k_gemm<<<gemm_grid0, dim3(256), 0, stream>>>(x, IN_C, W0 + 2 * IN_C * HID, HID,
                                                 b0 + 2 * HID, t2, HID, n, HID, IN_C);

    // SpMMs @96ch: t1 -> h[:,96:192]; t2 -> tp -> h[:,192:288]
    dim3 sp96_grid((n + 7) / 8), sp96_blk(192);   // C4=24, NPB=8
    k_spmm<24, 8><<<sp96_grid, sp96_blk, 0, stream>>>(t1, HID, h + HID, W0C, row_ptr, counts,
                                                      csr_src, csr_w, dinv, n);
    k_spmm<24, 8><<<sp96_grid, sp96_blk, 0, stream>>>(t2, HID, tp, HID, row_ptr, counts,
                                                      csr_src, csr_w, dinv, n);
    k_spmm<24, 8><<<sp96_grid, sp96_blk, 0, stream>>>(tp, HID, h + 2 * HID, W0C, row_ptr, counts,
                                                      csr_src, csr_w, dinv, n);

    // --- BN + ReLU on h (n,288) ---
    k_bn_prep<<<dim3(2), dim3(256), 0, stream>>>(bn_g, bn_b, bn_m, bn_v, bnscale, bnshift, W0C);
    int total4 = n * (W0C / 4);
    k_bn_relu<<<dim3((total4 + TB - 1) / TB), dim3(TB), 0, stream>>>((float4*)h, bnscale, bnshift,
                                                                     total4, W0C / 4);

    // --- layer 1: h(n,288) @ W1[j](288,64) ---
    dim3 gemm_grid1((n + BM - 1) / BM, 1);
    // j=0 -> g[:,0:64]
    k_gemm<<<gemm_grid1, dim3(256), 0, stream>>>(h, W0C, W1 + 0 * W0C * OUT_C, OUT_C,
                                                 b1 + 0 * OUT_C, g, W1C, n, OUT_C, W0C);
    k_gemm<<<gemm_grid1, dim3(256), 0, stream>>>(h, W0C, W1 + 1 * W0C * OUT_C, OUT_C,
                                                 b1 + 1 * OUT_C, u1, OUT_C, n, OUT_C, W0C);
    k_gemm<<<gemm_grid1, dim3(256), 0, stream>>>(h, W0C, W1 + 2 * W0C * OUT_C, OUT_C,
                                                 b1 + 2 * OUT_C, u2, OUT_C, n, OUT_C, W0C);

    // SpMMs @64ch: u1 -> g[:,64:128]; u2 -> up -> g[:,128:192]
    dim3 sp64_grid((n + 15) / 16), sp64_blk(256);  // C4=16, NPB=16
    k_spmm<16, 16><<<sp64_grid, sp64_blk, 0, stream>>>(u1, OUT_C, g + OUT_C, W1C, row_ptr, counts,
                                                       csr_src, csr_w, dinv, n);
    k_spmm<16, 16><<<sp64_grid, sp64_blk, 0, stream>>>(u2, OUT_C, up, OUT_C, row_ptr, counts,
                                                       csr_src, csr_w, dinv, n);
    k_spmm<16, 16><<<sp64_grid, sp64_blk, 0, stream>>>(up, OUT_C, g + 2 * OUT_C, W1C, row_ptr,
                                                       counts, csr_src, csr_w, dinv, n);

    // --- final projection: g(n,192) @ Wf(192,64) + bf -> out ---
    k_gemm<<<gemm_grid1, dim3(256), 0, stream>>>(g, W1C, Wf, OUT_C, bf, out, OUT_C,
                                                 n, OUT_C, W1C);
}

// Round 2
// 664.486 us; speedup vs baseline: 1.2320x; 1.2320x over previous
//
#include <hip/hip_runtime.h>

#define IN_C 128
#define HID 96
#define OUT_C 64
#define W0C 288   // HID*3  (BN width)
#define W1C 192   // OUT_C*3

// ---------------- graph preprocessing ----------------

__global__ void k_zero(int* __restrict__ p, int n) {
    int i = blockIdx.x * blockDim.x + threadIdx.x;
    if (i < n) p[i] = 0;
}

__global__ void k_count(const int* __restrict__ col, int* __restrict__ counts, int e) {
    int i = blockIdx.x * blockDim.x + threadIdx.x;
    if (i < e) atomicAdd(&counts[col[i]], 1);
}

__global__ void k_dinv(const int* __restrict__ counts, float* __restrict__ dinv, int n) {
    int i = blockIdx.x * blockDim.x + threadIdx.x;
    if (i < n) dinv[i] = rsqrtf((float)(counts[i] + 1));
}

__global__ void k_block_sum(const int* __restrict__ counts, int* __restrict__ bsums, int n) {
    __shared__ int s[256];
    int i = blockIdx.x * 256 + threadIdx.x;
    s[threadIdx.x] = (i < n) ? counts[i] : 0;
    __syncthreads();
    for (int off = 128; off > 0; off >>= 1) {
        if (threadIdx.x < (unsigned)off) s[threadIdx.x] += s[threadIdx.x + off];
        __syncthreads();
    }
    if (threadIdx.x == 0) bsums[blockIdx.x] = s[0];
}

// single block; nb <= 256 (n=50000 -> nb=196)
__global__ void k_scan_bsums(int* __restrict__ bsums, int nb) {
    __shared__ int s[256];
    int v = ((int)threadIdx.x < nb) ? bsums[threadIdx.x] : 0;
    s[threadIdx.x] = v;
    __syncthreads();
    for (int off = 1; off < 256; off <<= 1) {
        int t = ((int)threadIdx.x >= off) ? s[threadIdx.x - off] : 0;
        __syncthreads();
        s[threadIdx.x] += t;
        __syncthreads();
    }
    if ((int)threadIdx.x < nb) bsums[threadIdx.x] = s[threadIdx.x] - v;  // exclusive
}

__global__ void k_row_ptr(const int* __restrict__ counts, const int* __restrict__ boffs,
                          int* __restrict__ row_ptr, int n) {
    __shared__ int s[256];
    int i = blockIdx.x * 256 + threadIdx.x;
    int v = (i < n) ? counts[i] : 0;
    s[threadIdx.x] = v;
    __syncthreads();
    for (int off = 1; off < 256; off <<= 1) {
        int t = ((int)threadIdx.x >= off) ? s[threadIdx.x - off] : 0;
        __syncthreads();
        s[threadIdx.x] += t;
        __syncthreads();
    }
    if (i < n) row_ptr[i] = boffs[blockIdx.x] + s[threadIdx.x] - v;  // exclusive
}

__global__ void k_fill(const int* __restrict__ row, const int* __restrict__ col,
                       const int* __restrict__ row_ptr, int* __restrict__ cursor,
                       const float* __restrict__ dinv,
                       int* __restrict__ csr_src, float* __restrict__ csr_w, int e) {
    int i = blockIdx.x * blockDim.x + threadIdx.x;
    if (i >= e) return;
    int c = col[i], r = row[i];
    int pos = row_ptr[c] + atomicAdd(&cursor[c], 1);
    csr_src[pos] = r;
    csr_w[pos] = dinv[r] * dinv[c];
}

// ---------------- SpMM (CSR by destination, gather, no atomics) ----------------
// out[node, :] = dinv[node]^2 * x[node, :] + sum_k w[k] * x[src[k], :]
// Optional fused BN(eval)+ReLU epilogue (scale/shift indexed by chan0 + channel).
template <int C4, int NPB, bool BNRELU>
__global__ void k_spmm(const float* __restrict__ xin, int ldx,
                       float* __restrict__ xout, int ldo,
                       const int* __restrict__ row_ptr, const int* __restrict__ counts,
                       const int* __restrict__ csr_src, const float* __restrict__ csr_w,
                       const float* __restrict__ dinv, int n,
                       const float* __restrict__ scale, const float* __restrict__ shift,
                       int chan0) {
    int c4 = threadIdx.x % C4;
    int nl = threadIdx.x / C4;
    int node = blockIdx.x * NPB + nl;
    if (node >= n) return;
    const float4* xi = (const float4*)xin;
    int ldx4 = ldx >> 2, ldo4 = ldo >> 2;
    float di = dinv[node];
    float lw = di * di;
    float4 v = xi[(size_t)node * ldx4 + c4];
    float4 acc;
    acc.x = lw * v.x; acc.y = lw * v.y; acc.z = lw * v.z; acc.w = lw * v.w;
    int start = row_ptr[node];
    int cnt = counts[node];
    for (int k = 0; k < cnt; k++) {
        int src = csr_src[start + k];
        float w = csr_w[start + k];
        float4 xv = xi[(size_t)src * ldx4 + c4];
        acc.x += w * xv.x; acc.y += w * xv.y; acc.z += w * xv.z; acc.w += w * xv.w;
    }
    if (BNRELU) {
        float4 sc = ((const float4*)scale)[(chan0 >> 2) + c4];
        float4 sh = ((const float4*)shift)[(chan0 >> 2) + c4];
        acc.x = fmaxf(acc.x * sc.x + sh.x, 0.f);
        acc.y = fmaxf(acc.y * sc.y + sh.y, 0.f);
        acc.z = fmaxf(acc.z * sc.z + sh.z, 0.f);
        acc.w = fmaxf(acc.w * sc.w + sh.w, 0.f);
    }
    ((float4*)xout)[(size_t)node * ldo4 + c4] = acc;
}

// ---------------- tiled fp32 GEMM: C = A(MxK) @ B(KxN) + bias ----------------
// BM=64, BK=32, BN = 16*TNC (64 or 96). 256 threads, 4 x TNC outputs each.
// As stored [BK][BM+4] (pad -> <=2-way bank conflict on transposed stage writes,
// 16B-aligned ds_read_b128 fragment loads). Requires K%32==0, N%BN==0.
// Optional fused BN+ReLU epilogue.
template <int TNC, bool BNRELU>
__global__ __launch_bounds__(256) void k_gemm(const float* __restrict__ A, int lda,
                                              const float* __restrict__ B, int ldb,
                                              const float* __restrict__ bias,
                                              float* __restrict__ C, int ldc,
                                              int M, int N, int K,
                                              const float* __restrict__ scale,
                                              const float* __restrict__ shift, int chan0) {
    const int BNt = 16 * TNC;
    __shared__ float As[32][68];        // [BK][BM+4]
    __shared__ float Bs[32][BNt + 4];
    int tid = threadIdx.x;
    int tx = tid % 16, ty = tid / 16;
    int rowBase = blockIdx.x * 64;
    int colBase = blockIdx.y * BNt;
    float acc[4][TNC] = {};
    for (int k0 = 0; k0 < K; k0 += 32) {
        // stage A: 64 rows x 32 cols = 512 float4, 2 per thread, transpose in regs
#pragma unroll
        for (int s = 0; s < 2; s++) {
            int i4 = tid + s * 256;
            int r = i4 >> 3, c4 = i4 & 7;
            int gr = rowBase + r;
            float4 v = make_float4(0.f, 0.f, 0.f, 0.f);
            if (gr < M) v = *(const float4*)&A[(size_t)gr * lda + k0 + c4 * 4];
            As[c4 * 4 + 0][r] = v.x;
            As[c4 * 4 + 1][r] = v.y;
            As[c4 * 4 + 2][r] = v.z;
            As[c4 * 4 + 3][r] = v.w;
        }
        // stage B: 32 rows x BNt cols
#pragma unroll
        for (int i4 = tid; i4 < 32 * (BNt / 4); i4 += 256) {
            int r = i4 / (BNt / 4), c4 = i4 % (BNt / 4);
            float4 v = *(const float4*)&B[(size_t)(k0 + r) * ldb + colBase + c4 * 4];
            *(float4*)&Bs[r][c4 * 4] = v;
        }
        __syncthreads();
#pragma unroll
        for (int kk = 0; kk < 32; kk++) {
            float a[4], b[TNC];
            *(float4*)a = *(const float4*)&As[kk][ty * 4];
#pragma unroll
            for (int j = 0; j < TNC; j++) b[j] = Bs[kk][tx * TNC + j];
#pragma unroll
            for (int i = 0; i < 4; i++)
#pragma unroll
                for (int j = 0; j < TNC; j++) acc[i][j] += a[i] * b[j];
        }
        __syncthreads();
    }
#pragma unroll
    for (int i = 0; i < 4; i++) {
        int r = rowBase + ty * 4 + i;
        if (r >= M) continue;
#pragma unroll
        for (int j = 0; j < TNC; j++) {
            int c = colBase + tx * TNC + j;
            float v = acc[i][j] + bias[c];
            if (BNRELU) v = fmaxf(v * scale[chan0 + c] + shift[chan0 + c], 0.f);
            C[(size_t)r * ldc + c] = v;
        }
    }
}

// ---------------- BN param prep ----------------

__global__ void k_bn_prep(const float* __restrict__ gamma, const float* __restrict__ beta,
                          const float* __restrict__ mean, const float* __restrict__ var,
                          float* __restrict__ scale, float* __restrict__ shift, int w) {
    int i = blockIdx.x * blockDim.x + threadIdx.x;
    if (i < w) {
        float s = gamma[i] * rsqrtf(var[i] + 1e-5f);
        scale[i] = s;
        shift[i] = beta[i] - mean[i] * s;
    }
}

// ---------------- launch ----------------

extern "C" void kernel_launch(void* const* d_in, const int* in_sizes, int n_in,
                              void* d_out, int out_size, void* d_ws, size_t ws_size,
                              hipStream_t stream) {
    const int n = in_sizes[0] / IN_C;   // 50000
    const int e = in_sizes[1] / 2;      // 800000

    const float* x    = (const float*)d_in[0];
    const int*   ei   = (const int*)d_in[1];
    const float* W0   = (const float*)d_in[2];   // (3,128,96)
    const float* b0   = (const float*)d_in[3];   // (3,96)
    const float* W1   = (const float*)d_in[4];   // (3,288,64)
    const float* b1   = (const float*)d_in[5];   // (3,64)
    const float* bn_g = (const float*)d_in[6];
    const float* bn_b = (const float*)d_in[7];
    const float* bn_m = (const float*)d_in[8];
    const float* bn_v = (const float*)d_in[9];
    const float* Wf   = (const float*)d_in[10];  // (192,64)
    const float* bf   = (const float*)d_in[11];  // (64)
    float* out = (float*)d_out;

    const int* e_row = ei;
    const int* e_col = ei + e;

    // workspace layout (256B aligned)
    char* ws = (char*)d_ws;
    size_t off = 0;
    auto alloc = [&](size_t bytes) -> void* {
        void* p = ws + off;
        off += (bytes + 255) & ~(size_t)255;
        return p;
    };
    int*   counts  = (int*)alloc((size_t)2 * n * 4);   // counts + cursor contiguous
    int*   cursor  = counts + n;
    int*   row_ptr = (int*)alloc((size_t)n * 4);
    int*   bsums   = (int*)alloc(256 * 4);
    float* dinv    = (float*)alloc((size_t)n * 4);
    int*   csr_src = (int*)alloc((size_t)e * 4);
    float* csr_w   = (float*)alloc((size_t)e * 4);
    float* bnscale = (float*)alloc(W0C * 4);
    float* bnshift = (float*)alloc(W0C * 4);
    float* t1 = (float*)alloc((size_t)n * HID * 4);
    float* t2 = (float*)alloc((size_t)n * HID * 4);
    float* tp = (float*)alloc((size_t)n * HID * 4);
    float* h  = (float*)alloc((size_t)n * W0C * 4);
    float* g  = (float*)alloc((size_t)n * W1C * 4);
    // layer-1 temp buffers alias the (dead-by-then) t buffers
    float* u1 = t1;
    float* u2 = t2;
    float* up = tp;

    const int TB = 256;
    int nb = (n + 255) / 256;  // 196 (<=256 required by k_scan_bsums)

    // --- graph prep ---
    k_zero<<<dim3((2 * n + TB - 1) / TB), dim3(TB), 0, stream>>>(counts, 2 * n);
    k_count<<<dim3((e + TB - 1) / TB), dim3(TB), 0, stream>>>(e_col, counts, e);
    k_dinv<<<dim3((n + TB - 1) / TB), dim3(TB), 0, stream>>>(counts, dinv, n);
    k_block_sum<<<dim3(nb), dim3(256), 0, stream>>>(counts, bsums, n);
    k_scan_bsums<<<dim3(1), dim3(256), 0, stream>>>(bsums, nb);
    k_row_ptr<<<dim3(nb), dim3(256), 0, stream>>>(counts, bsums, row_ptr, n);
    k_fill<<<dim3((e + TB - 1) / TB), dim3(TB), 0, stream>>>(e_row, e_col, row_ptr, cursor,
                                                             dinv, csr_src, csr_w, e);
    k_bn_prep<<<dim3(2), dim3(256), 0, stream>>>(bn_g, bn_b, bn_m, bn_v, bnscale, bnshift, W0C);

    // --- layer 0: x(n,128) @ W0[j](128,96) ---
    dim3 gemm_grid(( n + 63) / 64, 1);
    // j=0 -> h[:,0:96] with fused BN+ReLU (channels 0..95)
    k_gemm<6, true><<<gemm_grid, dim3(256), 0, stream>>>(x, IN_C, W0 + 0 * IN_C * HID, HID,
                                                         b0 + 0 * HID, h, W0C, n, HID, IN_C,
                                                         bnscale, bnshift, 0);
    // j=1 -> t1 ; j=2 -> t2 (raw)
    k_gemm<6, false><<<gemm_grid, dim3(256), 0, stream>>>(x, IN_C, W0 + 1 * IN_C * HID, HID,
                                                          b0 + 1 * HID, t1, HID, n, HID, IN_C,
                                                          nullptr, nullptr, 0);
    k_gemm<6, false><<<gemm_grid, dim3(256), 0, stream>>>(x, IN_C, W0 + 2 * IN_C * HID, HID,
                                                          b0 + 2 * HID, t2, HID, n, HID, IN_C,
                                                          nullptr, nullptr, 0);

    // SpMMs @96ch: t1 -> h[:,96:192] (BN ch 96..191); t2 -> tp (raw) -> h[:,192:288] (BN)
    dim3 sp96_grid((n + 7) / 8), sp96_blk(192);   // C4=24, NPB=8
    k_spmm<24, 8, true><<<sp96_grid, sp96_blk, 0, stream>>>(t1, HID, h + HID, W0C, row_ptr, counts,
                                                            csr_src, csr_w, dinv, n,
                                                            bnscale, bnshift, HID);
    k_spmm<24, 8, false><<<sp96_grid, sp96_blk, 0, stream>>>(t2, HID, tp, HID, row_ptr, counts,
                                                             csr_src, csr_w, dinv, n,
                                                             nullptr, nullptr, 0);
    k_spmm<24, 8, true><<<sp96_grid, sp96_blk, 0, stream>>>(tp, HID, h + 2 * HID, W0C, row_ptr,
                                                            counts, csr_src, csr_w, dinv, n,
                                                            bnscale, bnshift, 2 * HID);

    // --- layer 1: h(n,288) @ W1[j](288,64) ---
    k_gemm<4, false><<<gemm_grid, dim3(256), 0, stream>>>(h, W0C, W1 + 0 * W0C * OUT_C, OUT_C,
                                                          b1 + 0 * OUT_C, g, W1C, n, OUT_C, W0C,
                                                          nullptr, nullptr, 0);
    k_gemm<4, false><<<gemm_grid, dim3(256), 0, stream>>>(h, W0C, W1 + 1 * W0C * OUT_C, OUT_C,
                                                          b1 + 1 * OUT_C, u1, OUT_C, n, OUT_C, W0C,
                                                          nullptr, nullptr, 0);
    k_gemm<4, false><<<gemm_grid, dim3(256), 0, stream>>>(h, W0C, W1 + 2 * W0C * OUT_C, OUT_C,
                                                          b1 + 2 * OUT_C, u2, OUT_C, n, OUT_C, W0C,
                                                          nullptr, nullptr, 0);

    // SpMMs @64ch: u1 -> g[:,64:128]; u2 -> up -> g[:,128:192]
    dim3 sp64_grid((n + 15) / 16), sp64_blk(256);  // C4=16, NPB=16
    k_spmm<16, 16, false><<<sp64_grid, sp64_blk, 0, stream>>>(u1, OUT_C, g + OUT_C, W1C, row_ptr,
                                                              counts, csr_src, csr_w, dinv, n,
                                                              nullptr, nullptr, 0);
    k_spmm<16, 16, false><<<sp64_grid, sp64_blk, 0, stream>>>(u2, OUT_C, up, OUT_C, row_ptr,
                                                              counts, csr_src, csr_w, dinv, n,
                                                              nullptr, nullptr, 0);
    k_spmm<16, 16, false><<<sp64_grid, sp64_blk, 0, stream>>>(up, OUT_C, g + 2 * OUT_C, W1C,
                                                              row_ptr, counts, csr_src, csr_w,
                                                              dinv, n, nullptr, nullptr, 0);

    // --- final projection: g(n,192) @ Wf(192,64) + bf -> out ---
    k_gemm<4, false><<<gemm_grid, dim3(256), 0, stream>>>(g, W1C, Wf, OUT_C, bf, out, OUT_C,
                                                          n, OUT_C, W1C, nullptr, nullptr, 0);
}